// Round 4
// baseline (546.036 us; speedup 1.0000x reference)
//
#include <hip/hip_runtime.h>
#include <hip/hip_bf16.h>
#include <stdint.h>

// Problem constants
#define HEADS 16
#define DH    64
#define NB    8
#define MQ    256     // latents per batch
#define MX    4096    // media tokens per batch
#define JD    4352    // MX + MQ
#define DIMV  1024
#define GK    1024    // K dim of every GEMM in this problem (compile-time)

typedef __bf16 bf16;
typedef __bf16 bf16x8 __attribute__((ext_vector_type(8)));
typedef float  f32x4  __attribute__((ext_vector_type(4)));

// XOR swizzle of 16B chunks within a 64-col (8-chunk) LDS row: spreads the
// stride-128B row aliasing across all banks. Same formula on stage + read.
#define SWZ(r, c) (((c) ^ ((r) & 7)))

#define VMW(n) asm volatile("s_waitcnt vmcnt(" #n ")" ::: "memory")

__device__ __forceinline__ void gl_lds16(const void* g, void* l) {
  __builtin_amdgcn_global_load_lds((const __attribute__((address_space(1))) void*)g,
                                   (__attribute__((address_space(3))) void*)l, 16, 0, 0);
}

// ---------------- LayerNorm (f32 in, bf16 out) -------------------------------
__global__ __launch_bounds__(256) void ln_kernel(
    const float* __restrict__ X, const float* __restrict__ gw, const float* __restrict__ bw,
    bf16* __restrict__ out_kv, bf16* __restrict__ out_ln, int is_lat)
{
  const int row = blockIdx.x;
  const int tid = threadIdx.x;
  const float4 v = ((const float4*)(X + (size_t)row * DIMV))[tid];
  float s  = v.x + v.y + v.z + v.w;
  float s2 = v.x*v.x + v.y*v.y + v.z*v.z + v.w*v.w;
#pragma unroll
  for (int m = 1; m < 64; m <<= 1) { s += __shfl_xor(s, m); s2 += __shfl_xor(s2, m); }
  __shared__ float red[8];
  const int wid = tid >> 6;
  if ((tid & 63) == 0) { red[wid*2] = s; red[wid*2+1] = s2; }
  __syncthreads();
  s  = red[0] + red[2] + red[4] + red[6];
  s2 = red[1] + red[3] + red[5] + red[7];
  const float mu  = s * (1.0f / DIMV);
  const float var = s2 * (1.0f / DIMV) - mu * mu;
  const float rst = rsqrtf(var + 1e-5f);
  const float4 g4 = ((const float4*)gw)[tid];
  const float4 b4 = ((const float4*)bw)[tid];
  union { bf16 h[4]; short4 s4; } u;
  u.h[0] = (bf16)((v.x - mu) * rst * g4.x + b4.x);
  u.h[1] = (bf16)((v.y - mu) * rst * g4.y + b4.y);
  u.h[2] = (bf16)((v.z - mu) * rst * g4.z + b4.z);
  u.h[3] = (bf16)((v.w - mu) * rst * g4.w + b4.w);
  size_t kvrow;
  if (is_lat) { int b = row >> 8;  int i = row & 255;  kvrow = (size_t)b * JD + MX + i; }
  else        { int b = row >> 12; int j = row & 4095; kvrow = (size_t)b * JD + j; }
  *(short4*)(out_kv + kvrow * DIMV + tid * 4) = u.s4;
  if (is_lat) *(short4*)(out_ln + (size_t)row * DIMV + tid * 4) = u.s4;
}

// ---------------- Weight transpose + f32->bf16: in[R][C] -> out[C][R] --------
__global__ __launch_bounds__(256) void transpose_w(
    const float* __restrict__ in, bf16* __restrict__ out, int R, int C)
{
  __shared__ float t[64][65];
  const int tilesC = C >> 6;
  const int tc = blockIdx.x % tilesC, tr = blockIdx.x / tilesC;
  const int r0 = tr << 6, c0 = tc << 6;
  const int lr = threadIdx.x >> 4;
  const int lc = (threadIdx.x & 15) << 2;
#pragma unroll
  for (int p = 0; p < 4; p++) {
    float4 v = *(const float4*)&in[(size_t)(r0 + lr + p*16) * C + c0 + lc];
    t[lr + p*16][lc    ] = v.x; t[lr + p*16][lc + 1] = v.y;
    t[lr + p*16][lc + 2] = v.z; t[lr + p*16][lc + 3] = v.w;
  }
  __syncthreads();
#pragma unroll
  for (int p = 0; p < 4; p++) {
    const int oc = lr + p*16;
    union { bf16 h[4]; short4 s4; } u;
    u.h[0] = (bf16)t[lc    ][oc]; u.h[1] = (bf16)t[lc + 1][oc];
    u.h[2] = (bf16)t[lc + 2][oc]; u.h[3] = (bf16)t[lc + 3][oc];
    *(short4*)&out[(size_t)(c0 + oc) * R + r0 + lc] = u.s4;
  }
}

// ---------------- mask dtype detect + build ---------------------------------
__global__ __launch_bounds__(256) void mask_detect(
    const unsigned char* __restrict__ m, int n, int* __restrict__ flag)
{
  const int tid = threadIdx.x;
  int cnt = 0;
  for (int i = tid; i < n; i += 256) cnt += (m[i] != 0) ? 1 : 0;
#pragma unroll
  for (int mm = 1; mm < 64; mm <<= 1) cnt += __shfl_xor(cnt, mm);
  __shared__ int r4[4];
  if ((tid & 63) == 0) r4[tid >> 6] = cnt;
  __syncthreads();
  if (tid == 0) {
    int t = r4[0] + r4[1] + r4[2] + r4[3];
    flag[0] = (t * 16 > n * 5) ? 1 : 0;   // frac > 0.3125 -> byte mode
  }
}

__global__ __launch_bounds__(256) void mask_build(
    const void* __restrict__ mraw, const int* __restrict__ flag, float* __restrict__ mm)
{
  const int idx = blockIdx.x * 256 + threadIdx.x;   // < 34816
  const int b = idx / JD, j = idx - b * JD;
  float v = 1.0f;
  if (j < MX) {
    bool masked = (*flag) ? (((const unsigned char*)mraw)[b * MX + j] != 0)
                          : (((const int*)mraw)[b * MX + j] != 0);
    v = masked ? 0.0f : 1.0f;
  }
  mm[idx] = v;
}

// ---------------- GEMM: 256x256 tile, BK=64, read-ahead 8-phase pipeline -----
// 512 threads = 8 waves (2 M-waves x 4 N-waves), per-wave output 128x64.
// LDS 128 KiB: per double-buffer d: A[256][64] then B[256][64] (32 KiB each).
// Read-ahead: phase p issues the ds_reads for phase p+1 (A-frags, and the
// next half-tile's B-frags at ph3/ph7) BEFORE its opening barrier, so the
// LDS reads execute under phase p's MFMA cluster; the MFMA wait is then
// lgkmcnt(newer-only), ~free. Two af register sets (afA/afB) ping-pong per
// phase; two bf sets (bfA/bfB) ping-pong per half-tile.
// Staging (2 x gl_lds per phase, uniform): ph0/1: A-buf1(tb); ph2/3:
// B-buf0(ta2); ph4/5: A-buf0(ta2); ph6/7: B-buf1(tb2). Region-free proofs:
// each staged region's last reader finished >=1 phase + barrier earlier.
// vmcnt ledger (steady): entry 4 outstanding; ph3 pre-wait 10, tb = oldest
// 8 -> vmcnt(2) (before the buf1 prefetch); ph7 pre-wait 10, ta2 = oldest
// 8 -> vmcnt(2). Never drains to 0 until the peeled drain iteration.
// omode 0: Krows rows; omode 1: V^T (operands swapped); omode 2: Qrows rows.
__global__ __launch_bounds__(512, 2) void gemm256(
    const bf16* __restrict__ A, const bf16* __restrict__ Bt,
    const bf16* __restrict__ Aq, const bf16* __restrict__ Bq,
    bf16* __restrict__ outR, bf16* __restrict__ outVT, bf16* __restrict__ outQ)
{
  __shared__ bf16 sm[65536];                 // 128 KiB: [d][A 16384 | B 16384]

  const int tid = threadIdx.x;
  const int lane = tid & 63, wid = tid >> 6;
  const int wr = wid >> 2, wc = wid & 3;     // 2 x 4 wave grid
  const int lc = lane & 15, lq = lane >> 4;
  const int srow = tid >> 3, sc = tid & 7;
  const int ssw = SWZ(srow, sc) * 8;

  // XCD-bijective swizzle (1120 % 8 == 0): contiguous tile chunk per XCD.
  int bid = blockIdx.x;
  bid = (bid & 7) * 140 + (bid >> 3);

  const bf16 *Arow, *Brow;
  int m0, n0, omode;
  if (bid < 1088) {
    const int by = bid >> 3, bx = bid & 7;
    m0 = by * 256;
    if (bx < 4) { n0 = bx * 256;
      Arow = A  + (size_t)m0 * GK; Brow = Bt + (size_t)n0 * GK; omode = 0; }
    else        { n0 = 1024 + (bx - 4) * 256;
      Arow = Bt + (size_t)n0 * GK; Brow = A  + (size_t)m0 * GK; omode = 1; }
  } else {
    const int ix = bid - 1088;
    m0 = (ix >> 2) * 256; n0 = (ix & 3) * 256;
    Arow = Aq + (size_t)m0 * GK; Brow = Bq + (size_t)n0 * GK; omode = 2;
  }

  const bf16* Abase = Arow + (size_t)srow * GK + ssw;
  const bf16* Bbase = Brow + (size_t)srow * GK + ssw;

  // stage one 128-row half-tile (2 x global_load_lds per thread)
  auto stA = [&](int d, int h, int kt) {
#pragma unroll
    for (int l = 0; l < 2; ++l)
      gl_lds16(Abase + (size_t)(h*128 + l*64) * GK + kt * 64,
               &sm[d*32768 + (h*128 + l*64)*64 + tid*8]);
  };
  auto stB = [&](int d, int h, int kt) {
#pragma unroll
    for (int l = 0; l < 2; ++l)
      gl_lds16(Bbase + (size_t)(h*128 + l*64) * GK + kt * 64,
               &sm[d*32768 + 16384 + (h*128 + l*64)*64 + tid*8]);
  };

  f32x4 acc[8][4];
#pragma unroll
  for (int i = 0; i < 8; i++)
#pragma unroll
    for (int j = 0; j < 4; j++)
#pragma unroll
      for (int r = 0; r < 4; r++) acc[i][j][r] = 0.f;

  bf16x8 afA[2][2], afB[2][2], bfA[4][2], bfB[4][2];

// One phase. WAIT: optional vmcnt (must precede the prefetch).
// PBUF/PQ: buffer + m-quadrant the NEXT phase's A-frags come from -> NXT.
// PREFBF: also prefetch the next half-tile's B-frags from PBUF -> BFN.
// STAGE: 2 gl_lds. Then: barrier; 16 MFMA on CUR/BFC (QACC m-quadrant);
// barrier. (compiler's lgkmcnt before the MFMAs only covers the newer
// prefetch reads; CUR's reads completed under the previous MFMA cluster)
#define PH(WAIT, PBUF, PQ, NXT, PREFBF, BFN, STAGE_STMT, CUR, BFC, QACC)       \
  {                                                                            \
    WAIT;                                                                      \
    const bf16* Ap_ = sm + (PBUF)*32768;                                       \
    _Pragma("unroll") for (int mi = 0; mi < 2; ++mi)                           \
      _Pragma("unroll") for (int kk = 0; kk < 2; ++kk)                         \
        NXT[mi][kk] = *(const bf16x8*)&Ap_[(wr*128 + ((PQ)*2+mi)*16 + lc)*64   \
                                           + SWZ(lc, kk*4 + lq)*8];            \
    if (PREFBF) {                                                              \
      const bf16* Bp_ = sm + (PBUF)*32768 + 16384;                             \
      _Pragma("unroll") for (int n = 0; n < 4; ++n)                            \
        _Pragma("unroll") for (int kk = 0; kk < 2; ++kk)                       \
          BFN[n][kk] = *(const bf16x8*)&Bp_[(wc*64 + n*16 + lc)*64             \
                                            + SWZ(lc, kk*4 + lq)*8];           \
    }                                                                          \
    STAGE_STMT;                                                                \
    __builtin_amdgcn_s_barrier();                                              \
    __builtin_amdgcn_s_setprio(1);                                             \
    _Pragma("unroll") for (int kk = 0; kk < 2; ++kk)                           \
      _Pragma("unroll") for (int mi = 0; mi < 2; ++mi)                         \
        _Pragma("unroll") for (int n = 0; n < 4; ++n)                          \
          acc[(QACC)*2+mi][n] = __builtin_amdgcn_mfma_f32_16x16x32_bf16(       \
              CUR[mi][kk], BFC[n][kk], acc[(QACC)*2+mi][n], 0, 0, 0);          \
    __builtin_amdgcn_s_setprio(0);                                             \
    __builtin_amdgcn_s_barrier();                                              \
  }

  // Prologue: tile0 (B+A, buf0) + tile1 B (buf1); vmcnt(4) -> tile0 landed,
  // tile1-B's 4 loads in flight. Then preload bfA + afA(q0) from buf0.
  stB(0, 0, 0); stB(0, 1, 0);
  stA(0, 0, 0); stA(0, 1, 0);
  stB(1, 0, 1); stB(1, 1, 1);
  VMW(4);
  __builtin_amdgcn_s_barrier();
#pragma unroll
  for (int mi = 0; mi < 2; ++mi)
#pragma unroll
    for (int kk = 0; kk < 2; ++kk)
      afA[mi][kk] = *(const bf16x8*)&sm[(wr*128 + mi*16 + lc)*64 + SWZ(lc, kk*4 + lq)*8];
#pragma unroll
  for (int n = 0; n < 4; ++n)
#pragma unroll
    for (int kk = 0; kk < 2; ++kk)
      bfA[n][kk] = *(const bf16x8*)&sm[16384 + (wc*64 + n*16 + lc)*64 + SWZ(lc, kk*4 + lq)*8];

#pragma unroll 1
  for (int it = 0; it < 7; ++it) {
    const int tb = 2*it + 1, ta2 = 2*it + 2, tb2 = 2*it + 3;
    PH({},     0, 1, afB, 0, bfB, { stA(1, 0, tb);  }, afA, bfA, 0);
    PH({},     0, 2, afA, 0, bfB, { stA(1, 1, tb);  }, afB, bfA, 1);
    PH({},     0, 3, afB, 0, bfB, { stB(0, 0, ta2); }, afA, bfA, 2);
    PH(VMW(2), 1, 0, afA, 1, bfB, { stB(0, 1, ta2); }, afB, bfA, 3);
    PH({},     1, 1, afB, 0, bfA, { stA(0, 0, ta2); }, afA, bfB, 0);
    PH({},     1, 2, afA, 0, bfA, { stA(0, 1, ta2); }, afB, bfB, 1);
    PH({},     1, 3, afB, 0, bfA, { stB(1, 0, tb2); }, afA, bfB, 2);
    PH(VMW(2), 0, 0, afA, 1, bfA, { stB(1, 1, tb2); }, afB, bfB, 3);
  }
  // Drain iteration (tiles 14/15): stage only tile15's A; vmcnt(0) at ph3.
  PH({},     0, 1, afB, 0, bfB, { stA(1, 0, 15); }, afA, bfA, 0);
  PH({},     0, 2, afA, 0, bfB, { stA(1, 1, 15); }, afB, bfA, 1);
  PH({},     0, 3, afB, 0, bfB, {}, afA, bfA, 2);
  PH(VMW(0), 1, 0, afA, 1, bfB, {}, afB, bfA, 3);
  PH({},     1, 1, afB, 0, bfA, {}, afA, bfB, 0);
  PH({},     1, 2, afA, 0, bfA, {}, afB, bfB, 1);
  PH({},     1, 3, afB, 0, bfA, {}, afA, bfB, 2);
  // Final phase (q3 of tile15): no prefetch/stage.
  __builtin_amdgcn_s_barrier();
  __builtin_amdgcn_s_setprio(1);
#pragma unroll
  for (int kk = 0; kk < 2; ++kk)
#pragma unroll
    for (int mi = 0; mi < 2; ++mi)
#pragma unroll
      for (int n = 0; n < 4; ++n)
        acc[6+mi][n] = __builtin_amdgcn_mfma_f32_16x16x32_bf16(
            afB[mi][kk], bfB[n][kk], acc[6+mi][n], 0, 0, 0);
  __builtin_amdgcn_s_setprio(0);
#undef PH

  // ---- Epilogue: acc -> bf16 Ct[256][256] in LDS (32-chunk swizzle), then
  //      coalesced 16B row-major stores.
  __syncthreads();
  bf16* Ct = sm;
#pragma unroll
  for (int m = 0; m < 8; ++m)
#pragma unroll
    for (int n = 0; n < 4; ++n) {
      const int col = wc*64 + n*16 + lc;
      const int cch = col >> 3, cw = col & 7;
#pragma unroll
      for (int r = 0; r < 4; ++r) {
        const int row = wr*128 + m*16 + lq*4 + r;
        Ct[row*256 + (((cch ^ (row & 31)) << 3) + cw)] = (bf16)acc[m][n][r];
      }
    }
  __syncthreads();

  const int cch = tid & 31, r0 = tid >> 5;
  if (omode != 1) {
    bf16* dst0 = (omode == 0 ? outR : outQ);
#pragma unroll
    for (int i = 0; i < 16; ++i) {
      const int row = r0 + i*16;
      bf16x8 v = *(const bf16x8*)&Ct[row*256 + ((cch ^ (row & 31)) << 3)];
      *(bf16x8*)(dst0 + (size_t)(m0 + row) * 1024 + n0 + cch*8) = v;
    }
  } else {
    const int bb = m0 / JD;                // 256-row m-tiles never cross batches (JD = 17*256)
    const int jbase = m0 - bb * JD;
#pragma unroll
    for (int i = 0; i < 16; ++i) {
      const int row = r0 + i*16;
      const int cc = n0 + row - 1024;      // weight col in V half
      bf16x8 v = *(const bf16x8*)&Ct[row*256 + ((cch ^ (row & 31)) << 3)];
      bf16* dst = outVT + (((size_t)(bb*HEADS + (cc >> 6)))*64 + (cc & 63)) * JD
                        + jbase + cch*8;
      *(bf16x8*)dst = v;
    }
  }
}

// ---------------- GEMM: 128x128 tile, BK=64 (final projection, f32 out) -----
__global__ __launch_bounds__(256) void gemm128(
    const bf16* __restrict__ A, const bf16* __restrict__ Bt,
    float* __restrict__ Cf, int N)
{
  __shared__ bf16 smem[2 * 128 * 64];
  bf16* As = smem;
  bf16* Bs = smem + 128 * 64;

  const int tid = threadIdx.x;
  const int lane = tid & 63, wid = tid >> 6;
  const int wr = wid >> 1, wc = wid & 1;
  const int m0 = blockIdx.y * 128;
  const int n0 = blockIdx.x * 128;
  const int srow = tid >> 3, sc = tid & 7;
  const int ssw = SWZ(srow, sc) * 8;     // swizzled source chunk (elements)
  const int lc = lane & 15, lq = lane >> 4;

  f32x4 acc[4][4];
#pragma unroll
  for (int i = 0; i < 4; i++)
#pragma unroll
    for (int j = 0; j < 4; j++)
#pragma unroll
      for (int r = 0; r < 4; r++) acc[i][j][r] = 0.f;

  const bf16* Abase = A + (size_t)m0 * GK + (size_t)srow * GK + ssw;
  const bf16* Bbase = Bt + (size_t)n0 * GK + (size_t)srow * GK + ssw;

  for (int k0 = 0; k0 < GK; k0 += 64) {
    __syncthreads();
#pragma unroll
    for (int q = 0; q < 4; q++) {
      gl_lds16(Abase + (size_t)q * 32 * GK + k0, &As[(srow + q*32) * 64 + sc*8]);
      gl_lds16(Bbase + (size_t)q * 32 * GK + k0, &Bs[(srow + q*32) * 64 + sc*8]);
    }
    VMW(0);
    __syncthreads();
#pragma unroll
    for (int kk = 0; kk < 2; kk++) {
      bf16x8 af[4], bfr[4];
#pragma unroll
      for (int mi = 0; mi < 4; mi++)
        af[mi] = *(const bf16x8*)&As[(wr*64 + mi*16 + lc) * 64 + SWZ(lc, kk*4 + lq)*8];
#pragma unroll
      for (int ni = 0; ni < 4; ni++)
        bfr[ni] = *(const bf16x8*)&Bs[(wc*64 + ni*16 + lc) * 64 + SWZ(lc, kk*4 + lq)*8];
#pragma unroll
      for (int mi = 0; mi < 4; mi++)
#pragma unroll
        for (int ni = 0; ni < 4; ni++)
          acc[mi][ni] = __builtin_amdgcn_mfma_f32_16x16x32_bf16(af[mi], bfr[ni], acc[mi][ni], 0, 0, 0);
    }
  }

#pragma unroll
  for (int mi = 0; mi < 4; mi++)
#pragma unroll
    for (int ni = 0; ni < 4; ni++) {
      const int r = m0 + wr*64 + mi*16 + lq*4;
      const int c = n0 + wc*64 + ni*16 + lc;
#pragma unroll
      for (int reg = 0; reg < 4; reg++)
        Cf[(size_t)(r + reg) * N + c] = acc[mi][ni][reg];
    }
}

// ---------------- Attention --------------------------------------------------
// 256 blocks = (b,h) x 2 q-tiles of 128; 512 threads (8 waves, 16 q-rows each).
// K/V double-buffered in LDS with counted vmcnt(2): tile t+2 staged after the
// compute barrier; wait covers tile t+1 (issued a full iteration earlier).
__global__ __launch_bounds__(512) void attn_kernel(
    const bf16* __restrict__ Qrows,  // [2048][1024]
    const bf16* __restrict__ Krows,  // [B*JD][1024]
    const bf16* __restrict__ VT,     // [B][H][64][JD]
    const float* __restrict__ mmul,  // [B][JD]
    bf16* __restrict__ outp)         // [2048][1024]
{
  const int bh = blockIdx.x >> 1, qt = blockIdx.x & 1;
  const int b = bh >> 4, h = bh & 15;
  __shared__ bf16 Qs[128 * 64];
  __shared__ bf16 Ks[2][64 * 64];
  __shared__ bf16 VTs[2][64 * 64];
  __shared__ bf16 Ps[8][16 * 64];
  const int tid = threadIdx.x, lane = tid & 63, w = tid >> 6;
  const int lc = lane & 15, lq = lane >> 4;
  const int srow = tid >> 3, sc = tid & 7;
  const int ssw = SWZ(srow, sc) * 8;

  const bf16* Qg = Qrows + ((size_t)(b*MQ + qt*128)) * 1024 + h*64;
  const bf16* Kg = Krows + ((size_t)b * JD) * 1024 + h*64;
  const bf16* Vg = VT + ((size_t)bh * 64) * JD;

  auto stKV = [&](int c, int t) {
    gl_lds16(Kg + (size_t)(t*64 + srow) * 1024 + ssw, &Ks[c][tid*8]);
    gl_lds16(Vg + (size_t)srow * JD + t*64 + ssw, &VTs[c][tid*8]);
  };

  gl_lds16(Qg + (size_t)srow * 1024 + ssw, &Qs[tid*8]);
  gl_lds16(Qg + (size_t)(srow + 64) * 1024 + ssw, &Qs[(tid + 512)*8]);
  stKV(0, 0);
  stKV(1, 1);
  VMW(2);                                   // Q + tile0 landed; tile1 in flight
  __syncthreads();

  bf16x8 qf[2];
#pragma unroll
  for (int kk = 0; kk < 2; kk++)
    qf[kk] = *(const bf16x8*)&Qs[(w*16 + lc) * 64 + SWZ(lc, kk*4 + lq)*8];

  f32x4 oacc[4];
  float den[4];
#pragma unroll
  for (int di = 0; di < 4; di++)
#pragma unroll
    for (int r = 0; r < 4; r++) oacc[di][r] = 0.f;
#pragma unroll
  for (int r = 0; r < 4; r++) den[r] = 0.f;

#pragma unroll 1
  for (int t = 0; t < JD/64; ++t) {
    const int c = t & 1;
    const int j0 = t * 64;

    // S = Q K^T
    f32x4 sacc[4];
#pragma unroll
    for (int nj = 0; nj < 4; nj++)
#pragma unroll
      for (int r = 0; r < 4; r++) sacc[nj][r] = 0.f;
#pragma unroll
    for (int kk = 0; kk < 2; kk++) {
      bf16x8 kf[4];
#pragma unroll
      for (int nj = 0; nj < 4; nj++)
        kf[nj] = *(const bf16x8*)&Ks[c][(nj*16 + lc) * 64 + SWZ(lc, kk*4 + lq)*8];
#pragma unroll
      for (int nj = 0; nj < 4; nj++)
        sacc[nj] = __builtin_amdgcn_mfma_f32_16x16x32_bf16(qf[kk], kf[nj], sacc[nj], 0, 0, 0);
    }

    // P = exp(S*scale) * mask ; partial denominators ; stage P for PV
#pragma unroll
    for (int nj = 0; nj < 4; nj++) {
      const float mm = mmul[b * JD + j0 + nj*16 + lc];
#pragma unroll
      for (int r = 0; r < 4; r++) {
        // scale * log2(e) = 0.125 * 1.4426950 = 0.18033688
        const float p = exp2f(sacc[nj][r] * 0.18033688f) * mm;
        den[r] += p;
        const int row = lq*4 + r, col = nj*16 + lc;
        Ps[w][row*64 + (((col >> 3) ^ (row & 7)) << 3) + (col & 7)] = (bf16)p;
      }
    }

    // O += P V
#pragma unroll
    for (int kk = 0; kk < 2; kk++) {
      bf16x8 pf = *(const bf16x8*)&Ps[w][lc*64 + SWZ(lc, kk*4 + lq)*8];
#pragma unroll
      for (int di = 0; di < 4; di++) {
        bf16x8 vf = *(const bf16x8*)&VTs[c][(di*16 + lc) * 64 + SWZ(lc, kk*4 + lq)*8];
        oacc[di] = __builtin_amdgcn_mfma_f32_16x16x32_bf16(pf, vf, oacc[di], 0, 0, 0);
      }
    }

    __builtin_amdgcn_s_barrier();           // all waves done with buf c
    if (t + 2 < JD/64) {
      stKV(c, t + 2);
      VMW(2);                               // tile t+1 landed; t+2 in flight
    } else if (t + 1 < JD/64) {
      VMW(0);                               // drain last prefetch
    }
    __builtin_amdgcn_s_barrier();
  }

#pragma unroll
  for (int r = 0; r < 4; r++) {
    float d = den[r];
    d += __shfl_xor(d, 1); d += __shfl_xor(d, 2);
    d += __shfl_xor(d, 4); d += __shfl_xor(d, 8);
    den[r] = 1.0f / d;
  }

#pragma unroll
  for (int di = 0; di < 4; di++) {
    const int col = h*64 + di*16 + lc;
#pragma unroll
    for (int r = 0; r < 4; r++) {
      const int i = qt*128 + w*16 + lq*4 + r;
      outp[(size_t)(b*MQ + i) * 1024 + col] = (bf16)(oacc[di][r] * den[r]);
    }
  }
}

// ---------------- launch -----------------------------------------------------
extern "C" void kernel_launch(void* const* d_in, const int* in_sizes, int n_in,
                              void* d_out, int out_size, void* d_ws, size_t ws_size,
                              hipStream_t stream)
{
  const float* x    = (const float*)d_in[0];
  const float* lat  = (const float*)d_in[1];
  const void*  mraw = d_in[2];
  const float* nm_g = (const float*)d_in[3];
  const float* nm_b = (const float*)d_in[4];
  const float* nl_g = (const float*)d_in[5];
  const float* nl_b = (const float*)d_in[6];
  const float* Wq   = (const float*)d_in[7];
  const float* Wkv  = (const float*)d_in[8];
  const float* Wo   = (const float*)d_in[9];
  float* out = (float*)d_out;

  char* p = (char*)d_ws;
  auto alloc = [&](size_t bytes) { char* r = p; p += (bytes + 255) & ~(size_t)255; return r; };

  bf16*  kv_in  = (bf16*)alloc((size_t)NB * JD * DIMV * 2);          // 71.3 MB
  bf16*  Krows  = (bf16*)alloc((size_t)NB * JD * 1024 * 2);          // 71.3 MB
  bf16*  VTbuf  = (bf16*)alloc((size_t)NB * HEADS * 64 * JD * 2);    // 71.3 MB
  bf16*  WqT    = (bf16*)alloc((size_t)1024 * 1024 * 2);
  bf16*  WkvT   = (bf16*)alloc((size_t)2048 * 1024 * 2);
  bf16*  WoT    = (bf16*)alloc((size_t)1024 * 1024 * 2);
  bf16*  ln_buf = (bf16*)alloc((size_t)NB * MQ * DIMV * 2);
  bf16*  Qrows  = (bf16*)alloc((size_t)NB * MQ * 1024 * 2);
  bf16*  attout = (bf16*)alloc((size_t)NB * MQ * DIMV * 2);
  float* mmulp  = (float*)alloc((size_t)NB * JD * 4);
  int*   flag   = (int*)alloc(256);
  (void)ws_size; (void)in_sizes; (void)n_in; (void)out_size;

  ln_kernel<<<NB * MX, 256, 0, stream>>>(x,   nm_g, nm_b, kv_in, nullptr, 0);
  ln_kernel<<<NB * MQ, 256, 0, stream>>>(lat, nl_g, nl_b, kv_in, ln_buf, 1);
  transpose_w<<<256, 256, 0, stream>>>(Wq,  WqT,  1024, 1024);
  transpose_w<<<512, 256, 0, stream>>>(Wkv, WkvT, 1024, 2048);
  transpose_w<<<256, 256, 0, stream>>>(Wo,  WoT,  1024, 1024);
  mask_detect<<<1, 256, 0, stream>>>((const unsigned char*)mraw, 32768, flag);
  mask_build<<<136, 256, 0, stream>>>(mraw, flag, mmulp);

  // kv = kv_in @ Wkv (K rows + V^T) AND q = ln @ Wq, all as 256^2 tiles:
  // 1088 KV tiles + 32 Q tiles = 1120 blocks (%8==0 for XCD swizzle).
  gemm256<<<1120, 512, 0, stream>>>(kv_in, WkvT, ln_buf, WqT, Krows, VTbuf, Qrows);
  attn_kernel<<<256, 512, 0, stream>>>(Qrows, Krows, VTbuf, mmulp, attout);
  // out = attout @ Wo -> f32 d_out
  gemm128<<<dim3(8, 16), 256, 0, stream>>>(attout, WoT, out, 1024);
}

// Round 5
// 524.547 us; speedup vs baseline: 1.0410x; 1.0410x over previous
//
#include <hip/hip_runtime.h>
#include <hip/hip_bf16.h>
#include <stdint.h>

// Problem constants
#define HEADS 16
#define DH    64
#define NB    8
#define MQ    256     // latents per batch
#define MX    4096    // media tokens per batch
#define JD    4352    // MX + MQ
#define DIMV  1024
#define GK    1024    // K dim of every GEMM in this problem (compile-time)

typedef __bf16 bf16;
typedef __bf16 bf16x8 __attribute__((ext_vector_type(8)));
typedef float  f32x4  __attribute__((ext_vector_type(4)));

// XOR swizzle of 16B chunks within a 64-col (8-chunk) LDS row: spreads the
// stride-128B row aliasing across all banks. Same formula on stage + read.
#define SWZ(r, c) (((c) ^ ((r) & 7)))

#define VMW(n) asm volatile("s_waitcnt vmcnt(" #n ")" ::: "memory")

__device__ __forceinline__ void gl_lds16(const void* g, void* l) {
  __builtin_amdgcn_global_load_lds((const __attribute__((address_space(1))) void*)g,
                                   (__attribute__((address_space(3))) void*)l, 16, 0, 0);
}

// ---------------- LayerNorm (f32 in, bf16 out) -------------------------------
__global__ __launch_bounds__(256) void ln_kernel(
    const float* __restrict__ X, const float* __restrict__ gw, const float* __restrict__ bw,
    bf16* __restrict__ out_kv, bf16* __restrict__ out_ln, int is_lat)
{
  const int row = blockIdx.x;
  const int tid = threadIdx.x;
  const float4 v = ((const float4*)(X + (size_t)row * DIMV))[tid];
  float s  = v.x + v.y + v.z + v.w;
  float s2 = v.x*v.x + v.y*v.y + v.z*v.z + v.w*v.w;
#pragma unroll
  for (int m = 1; m < 64; m <<= 1) { s += __shfl_xor(s, m); s2 += __shfl_xor(s2, m); }
  __shared__ float red[8];
  const int wid = tid >> 6;
  if ((tid & 63) == 0) { red[wid*2] = s; red[wid*2+1] = s2; }
  __syncthreads();
  s  = red[0] + red[2] + red[4] + red[6];
  s2 = red[1] + red[3] + red[5] + red[7];
  const float mu  = s * (1.0f / DIMV);
  const float var = s2 * (1.0f / DIMV) - mu * mu;
  const float rst = rsqrtf(var + 1e-5f);
  const float4 g4 = ((const float4*)gw)[tid];
  const float4 b4 = ((const float4*)bw)[tid];
  union { bf16 h[4]; short4 s4; } u;
  u.h[0] = (bf16)((v.x - mu) * rst * g4.x + b4.x);
  u.h[1] = (bf16)((v.y - mu) * rst * g4.y + b4.y);
  u.h[2] = (bf16)((v.z - mu) * rst * g4.z + b4.z);
  u.h[3] = (bf16)((v.w - mu) * rst * g4.w + b4.w);
  size_t kvrow;
  if (is_lat) { int b = row >> 8;  int i = row & 255;  kvrow = (size_t)b * JD + MX + i; }
  else        { int b = row >> 12; int j = row & 4095; kvrow = (size_t)b * JD + j; }
  *(short4*)(out_kv + kvrow * DIMV + tid * 4) = u.s4;
  if (is_lat) *(short4*)(out_ln + (size_t)row * DIMV + tid * 4) = u.s4;
}

// ---------------- Weight transpose + f32->bf16: in[R][C] -> out[C][R] --------
__global__ __launch_bounds__(256) void transpose_w(
    const float* __restrict__ in, bf16* __restrict__ out, int R, int C)
{
  __shared__ float t[64][65];
  const int tilesC = C >> 6;
  const int tc = blockIdx.x % tilesC, tr = blockIdx.x / tilesC;
  const int r0 = tr << 6, c0 = tc << 6;
  const int lr = threadIdx.x >> 4;
  const int lc = (threadIdx.x & 15) << 2;
#pragma unroll
  for (int p = 0; p < 4; p++) {
    float4 v = *(const float4*)&in[(size_t)(r0 + lr + p*16) * C + c0 + lc];
    t[lr + p*16][lc    ] = v.x; t[lr + p*16][lc + 1] = v.y;
    t[lr + p*16][lc + 2] = v.z; t[lr + p*16][lc + 3] = v.w;
  }
  __syncthreads();
#pragma unroll
  for (int p = 0; p < 4; p++) {
    const int oc = lr + p*16;
    union { bf16 h[4]; short4 s4; } u;
    u.h[0] = (bf16)t[lc    ][oc]; u.h[1] = (bf16)t[lc + 1][oc];
    u.h[2] = (bf16)t[lc + 2][oc]; u.h[3] = (bf16)t[lc + 3][oc];
    *(short4*)&out[(size_t)(c0 + oc) * R + r0 + lc] = u.s4;
  }
}

// ---------------- mask dtype detect + build ---------------------------------
__global__ __launch_bounds__(256) void mask_detect(
    const unsigned char* __restrict__ m, int n, int* __restrict__ flag)
{
  const int tid = threadIdx.x;
  int cnt = 0;
  for (int i = tid; i < n; i += 256) cnt += (m[i] != 0) ? 1 : 0;
#pragma unroll
  for (int mm = 1; mm < 64; mm <<= 1) cnt += __shfl_xor(cnt, mm);
  __shared__ int r4[4];
  if ((tid & 63) == 0) r4[tid >> 6] = cnt;
  __syncthreads();
  if (tid == 0) {
    int t = r4[0] + r4[1] + r4[2] + r4[3];
    flag[0] = (t * 16 > n * 5) ? 1 : 0;   // frac > 0.3125 -> byte mode
  }
}

__global__ __launch_bounds__(256) void mask_build(
    const void* __restrict__ mraw, const int* __restrict__ flag, float* __restrict__ mm)
{
  const int idx = blockIdx.x * 256 + threadIdx.x;   // < 34816
  const int b = idx / JD, j = idx - b * JD;
  float v = 1.0f;
  if (j < MX) {
    bool masked = (*flag) ? (((const unsigned char*)mraw)[b * MX + j] != 0)
                          : (((const int*)mraw)[b * MX + j] != 0);
    v = masked ? 0.0f : 1.0f;
  }
  mm[idx] = v;
}

// ---------------- GEMM: 256x256 tile, BK=64, m201-faithful 8-phase pipeline --
// (round-2 schedule, best measured: 175 us, VGPR 116 — read-ahead reverted)
__global__ __launch_bounds__(512, 2) void gemm256(
    const bf16* __restrict__ A, const bf16* __restrict__ Bt,
    const bf16* __restrict__ Aq, const bf16* __restrict__ Bq,
    bf16* __restrict__ outR, bf16* __restrict__ outVT, bf16* __restrict__ outQ)
{
  __shared__ bf16 sm[65536];                 // 128 KiB: [d][A 16384 | B 16384]

  const int tid = threadIdx.x;
  const int lane = tid & 63, wid = tid >> 6;
  const int wr = wid >> 2, wc = wid & 3;     // 2 x 4 wave grid
  const int lc = lane & 15, lq = lane >> 4;
  const int srow = tid >> 3, sc = tid & 7;
  const int ssw = SWZ(srow, sc) * 8;

  // XCD-bijective swizzle (1120 % 8 == 0): contiguous tile chunk per XCD.
  int bid = blockIdx.x;
  bid = (bid & 7) * 140 + (bid >> 3);

  const bf16 *Arow, *Brow;
  int m0, n0, omode;
  if (bid < 1088) {
    const int by = bid >> 3, bx = bid & 7;
    m0 = by * 256;
    if (bx < 4) { n0 = bx * 256;
      Arow = A  + (size_t)m0 * GK; Brow = Bt + (size_t)n0 * GK; omode = 0; }
    else        { n0 = 1024 + (bx - 4) * 256;
      Arow = Bt + (size_t)n0 * GK; Brow = A  + (size_t)m0 * GK; omode = 1; }
  } else {
    const int ix = bid - 1088;
    m0 = (ix >> 2) * 256; n0 = (ix & 3) * 256;
    Arow = Aq + (size_t)m0 * GK; Brow = Bq + (size_t)n0 * GK; omode = 2;
  }

  const bf16* Abase = Arow + (size_t)srow * GK + ssw;
  const bf16* Bbase = Brow + (size_t)srow * GK + ssw;

  // stage one 128-row half-tile (2 x global_load_lds per thread)
  auto stA = [&](int d, int h, int kt) {
#pragma unroll
    for (int l = 0; l < 2; ++l)
      gl_lds16(Abase + (size_t)(h*128 + l*64) * GK + kt * 64,
               &sm[d*32768 + (h*128 + l*64)*64 + tid*8]);
  };
  auto stB = [&](int d, int h, int kt) {
#pragma unroll
    for (int l = 0; l < 2; ++l)
      gl_lds16(Bbase + (size_t)(h*128 + l*64) * GK + kt * 64,
               &sm[d*32768 + 16384 + (h*128 + l*64)*64 + tid*8]);
  };

  f32x4 acc[8][4];
#pragma unroll
  for (int i = 0; i < 8; i++)
#pragma unroll
    for (int j = 0; j < 4; j++)
#pragma unroll
      for (int r = 0; r < 4; r++) acc[i][j][r] = 0.f;

#define DS_PHASE(d, q, STAGE_STMT, WAIT_STMT)                                  \
  {                                                                            \
    const bf16* As_ = sm + (d)*32768;                                          \
    const bf16* Bs_ = sm + (d)*32768 + 16384;                                  \
    bf16x8 af[2][2];                                                           \
    _Pragma("unroll") for (int mi = 0; mi < 2; ++mi)                           \
      _Pragma("unroll") for (int kk = 0; kk < 2; ++kk)                         \
        af[mi][kk] = *(const bf16x8*)&As_[(wr*128 + ((q)*2+mi)*16 + lc)*64 +   \
                                          SWZ(lc, kk*4 + lq)*8];               \
    if ((q) == 0) {                                                            \
      _Pragma("unroll") for (int n = 0; n < 4; ++n)                            \
        _Pragma("unroll") for (int kk = 0; kk < 2; ++kk)                       \
          bfrag[n][kk] = *(const bf16x8*)&Bs_[(wc*64 + n*16 + lc)*64 +         \
                                              SWZ(lc, kk*4 + lq)*8];           \
    }                                                                          \
    STAGE_STMT;                                                                \
    WAIT_STMT;                                                                 \
    __builtin_amdgcn_s_barrier();                                              \
    __builtin_amdgcn_s_setprio(1);                                             \
    _Pragma("unroll") for (int kk = 0; kk < 2; ++kk)                           \
      _Pragma("unroll") for (int mi = 0; mi < 2; ++mi)                         \
        _Pragma("unroll") for (int n = 0; n < 4; ++n)                          \
          acc[(q)*2+mi][n] = __builtin_amdgcn_mfma_f32_16x16x32_bf16(          \
              af[mi][kk], bfrag[n][kk], acc[(q)*2+mi][n], 0, 0, 0);            \
    __builtin_amdgcn_s_setprio(0);                                             \
    __builtin_amdgcn_s_barrier();                                              \
  }

  // Prologue: tile0 B+A, tile1 B; wait leaves tile1's B (4 loads) in flight.
  stB(0, 0, 0); stB(0, 1, 0);
  stA(0, 0, 0); stA(0, 1, 0);
  stB(1, 0, 1); stB(1, 1, 1);
  VMW(4);
  __builtin_amdgcn_s_barrier();

  bf16x8 bfrag[4][2];
#pragma unroll 1
  for (int it = 0; it < 8; ++it) {
    const int tb = 2*it + 1, ta2 = 2*it + 2, tb2 = 2*it + 3;
    const bool s2 = (ta2 < 16), s3 = (tb2 < 16);
    DS_PHASE(0, 0, { stA(1, 0, tb); stA(1, 1, tb); }, {});
    DS_PHASE(0, 1, { if (s2) stB(0, 0, ta2); }, {});
    DS_PHASE(0, 2, { if (s2) stB(0, 1, ta2); }, {});
    DS_PHASE(0, 3, {}, { if (s2) { VMW(4); } else { VMW(0); } });
    DS_PHASE(1, 0, { if (s2) stA(0, 0, ta2); }, {});
    DS_PHASE(1, 1, { if (s2) stA(0, 1, ta2); }, {});
    DS_PHASE(1, 2, { if (s3) stB(1, 0, tb2); }, {});
    DS_PHASE(1, 3, { if (s3) stB(1, 1, tb2); }, { if (s3) { VMW(4); } });
  }
#undef DS_PHASE

  // ---- Epilogue: acc -> bf16 Ct[256][256] in LDS (32-chunk swizzle), then
  //      coalesced 16B row-major stores.
  __syncthreads();
  bf16* Ct = sm;
#pragma unroll
  for (int m = 0; m < 8; ++m)
#pragma unroll
    for (int n = 0; n < 4; ++n) {
      const int col = wc*64 + n*16 + lc;
      const int cch = col >> 3, cw = col & 7;
#pragma unroll
      for (int r = 0; r < 4; ++r) {
        const int row = wr*128 + m*16 + lq*4 + r;
        Ct[row*256 + (((cch ^ (row & 31)) << 3) + cw)] = (bf16)acc[m][n][r];
      }
    }
  __syncthreads();

  const int cch = tid & 31, r0 = tid >> 5;
  if (omode != 1) {
    bf16* dst0 = (omode == 0 ? outR : outQ);
#pragma unroll
    for (int i = 0; i < 16; ++i) {
      const int row = r0 + i*16;
      bf16x8 v = *(const bf16x8*)&Ct[row*256 + ((cch ^ (row & 31)) << 3)];
      *(bf16x8*)(dst0 + (size_t)(m0 + row) * 1024 + n0 + cch*8) = v;
    }
  } else {
    const int bb = m0 / JD;                // 256-row m-tiles never cross batches (JD = 17*256)
    const int jbase = m0 - bb * JD;
#pragma unroll
    for (int i = 0; i < 16; ++i) {
      const int row = r0 + i*16;
      const int cc = n0 + row - 1024;      // weight col in V half
      bf16x8 v = *(const bf16x8*)&Ct[row*256 + ((cch ^ (row & 31)) << 3)];
      bf16* dst = outVT + (((size_t)(bb*HEADS + (cc >> 6)))*64 + (cc & 63)) * JD
                        + jbase + cch*8;
      *(bf16x8*)dst = v;
    }
  }
}

// ---------------- GEMM: 128x128 tile, BK=64 (final projection, f32 out) -----
__global__ __launch_bounds__(256) void gemm128(
    const bf16* __restrict__ A, const bf16* __restrict__ Bt,
    float* __restrict__ Cf, int N)
{
  __shared__ bf16 smem[2 * 128 * 64];
  bf16* As = smem;
  bf16* Bs = smem + 128 * 64;

  const int tid = threadIdx.x;
  const int lane = tid & 63, wid = tid >> 6;
  const int wr = wid >> 1, wc = wid & 1;
  const int m0 = blockIdx.y * 128;
  const int n0 = blockIdx.x * 128;
  const int srow = tid >> 3, sc = tid & 7;
  const int ssw = SWZ(srow, sc) * 8;     // swizzled source chunk (elements)
  const int lc = lane & 15, lq = lane >> 4;

  f32x4 acc[4][4];
#pragma unroll
  for (int i = 0; i < 4; i++)
#pragma unroll
    for (int j = 0; j < 4; j++)
#pragma unroll
      for (int r = 0; r < 4; r++) acc[i][j][r] = 0.f;

  const bf16* Abase = A + (size_t)m0 * GK + (size_t)srow * GK + ssw;
  const bf16* Bbase = Bt + (size_t)n0 * GK + (size_t)srow * GK + ssw;

  for (int k0 = 0; k0 < GK; k0 += 64) {
    __syncthreads();
#pragma unroll
    for (int q = 0; q < 4; q++) {
      gl_lds16(Abase + (size_t)q * 32 * GK + k0, &As[(srow + q*32) * 64 + sc*8]);
      gl_lds16(Bbase + (size_t)q * 32 * GK + k0, &Bs[(srow + q*32) * 64 + sc*8]);
    }
    VMW(0);
    __syncthreads();
#pragma unroll
    for (int kk = 0; kk < 2; kk++) {
      bf16x8 af[4], bfr[4];
#pragma unroll
      for (int mi = 0; mi < 4; mi++)
        af[mi] = *(const bf16x8*)&As[(wr*64 + mi*16 + lc) * 64 + SWZ(lc, kk*4 + lq)*8];
#pragma unroll
      for (int ni = 0; ni < 4; ni++)
        bfr[ni] = *(const bf16x8*)&Bs[(wc*64 + ni*16 + lc) * 64 + SWZ(lc, kk*4 + lq)*8];
#pragma unroll
      for (int mi = 0; mi < 4; mi++)
#pragma unroll
        for (int ni = 0; ni < 4; ni++)
          acc[mi][ni] = __builtin_amdgcn_mfma_f32_16x16x32_bf16(af[mi], bfr[ni], acc[mi][ni], 0, 0, 0);
    }
  }

#pragma unroll
  for (int mi = 0; mi < 4; mi++)
#pragma unroll
    for (int ni = 0; ni < 4; ni++) {
      const int r = m0 + wr*64 + mi*16 + lq*4;
      const int c = n0 + wc*64 + ni*16 + lc;
#pragma unroll
      for (int reg = 0; reg < 4; reg++)
        Cf[(size_t)(r + reg) * N + c] = acc[mi][ni][reg];
    }
}

// ---------------- Attention --------------------------------------------------
// 256 blocks = (b,h) x 2 q-tiles of 128; 512 threads (8 waves, 16 q-rows each).
// SWAPPED QK^T (T12 mechanism): sacc = mfma(kf, qf) -> S^T in C-layout, so a
// lane holds 4 CONSECUTIVE j (PV contraction dim) for fixed q = lane&15.
// P-staging becomes 4x ds_write_b64 (vs 16 scalar b16), mask becomes 4x
// float4 loads (vs 16 scalar), denominator becomes lane-local sum + 2 shfl.
// Ps layout: [16 q rows][64 j], 128 B row, 16B-chunk XOR swizzle c4^(q&7);
// byte<->j mapping preserved (write c4 = nj*2+(lq>>1), inner8 = lq&1; read
// c4 = kk*4+lq) -> PV A-frag b128 reads are write-consistent.
__global__ __launch_bounds__(512) void attn_kernel(
    const bf16* __restrict__ Qrows,  // [2048][1024]
    const bf16* __restrict__ Krows,  // [B*JD][1024]
    const bf16* __restrict__ VT,     // [B][H][64][JD]
    const float* __restrict__ mmul,  // [B][JD]
    bf16* __restrict__ outp)         // [2048][1024]
{
  const int bh = blockIdx.x >> 1, qt = blockIdx.x & 1;
  const int b = bh >> 4, h = bh & 15;
  __shared__ bf16 Qs[128 * 64];
  __shared__ bf16 Ks[2][64 * 64];
  __shared__ bf16 VTs[2][64 * 64];
  __shared__ bf16 Ps[8][16 * 64];
  const int tid = threadIdx.x, lane = tid & 63, w = tid >> 6;
  const int lc = lane & 15, lq = lane >> 4;
  const int srow = tid >> 3, sc = tid & 7;
  const int ssw = SWZ(srow, sc) * 8;

  const bf16* Qg = Qrows + ((size_t)(b*MQ + qt*128)) * 1024 + h*64;
  const bf16* Kg = Krows + ((size_t)b * JD) * 1024 + h*64;
  const bf16* Vg = VT + ((size_t)bh * 64) * JD;

  auto stKV = [&](int c, int t) {
    gl_lds16(Kg + (size_t)(t*64 + srow) * 1024 + ssw, &Ks[c][tid*8]);
    gl_lds16(Vg + (size_t)srow * JD + t*64 + ssw, &VTs[c][tid*8]);
  };

  gl_lds16(Qg + (size_t)srow * 1024 + ssw, &Qs[tid*8]);
  gl_lds16(Qg + (size_t)(srow + 64) * 1024 + ssw, &Qs[(tid + 512)*8]);
  stKV(0, 0);
  stKV(1, 1);
  VMW(2);                                   // Q + tile0 landed; tile1 in flight
  __syncthreads();

  bf16x8 qf[2];
#pragma unroll
  for (int kk = 0; kk < 2; kk++)
    qf[kk] = *(const bf16x8*)&Qs[(w*16 + lc) * 64 + SWZ(lc, kk*4 + lq)*8];

  char* PsW = (char*)&Ps[w][0];
  f32x4 oacc[4];
  float den = 0.f;
#pragma unroll
  for (int di = 0; di < 4; di++)
#pragma unroll
    for (int r = 0; r < 4; r++) oacc[di][r] = 0.f;

#pragma unroll 1
  for (int t = 0; t < JD/64; ++t) {
    const int c = t & 1;
    const int j0 = t * 64;

    // S^T = K Q^T (swapped operands): sacc[nj][r] = S[q=lc][j0 + nj*16 + lq*4 + r]
    f32x4 sacc[4];
#pragma unroll
    for (int nj = 0; nj < 4; nj++)
#pragma unroll
      for (int r = 0; r < 4; r++) sacc[nj][r] = 0.f;
#pragma unroll
    for (int kk = 0; kk < 2; kk++) {
      bf16x8 kf[4];
#pragma unroll
      for (int nj = 0; nj < 4; nj++)
        kf[nj] = *(const bf16x8*)&Ks[c][(nj*16 + lc) * 64 + SWZ(lc, kk*4 + lq)*8];
#pragma unroll
      for (int nj = 0; nj < 4; nj++)
        sacc[nj] = __builtin_amdgcn_mfma_f32_16x16x32_bf16(kf[nj], qf[kk], sacc[nj], 0, 0, 0);
    }

    // P = exp(S*scale) * mask ; lane-local denominator ; packed b64 P-stage
#pragma unroll
    for (int nj = 0; nj < 4; nj++) {
      const float4 mm4 = *(const float4*)&mmul[b * JD + j0 + nj*16 + lq*4];
      // scale * log2(e) = 0.125 * 1.4426950 = 0.18033688
      const float p0 = exp2f(sacc[nj][0] * 0.18033688f) * mm4.x;
      const float p1 = exp2f(sacc[nj][1] * 0.18033688f) * mm4.y;
      const float p2 = exp2f(sacc[nj][2] * 0.18033688f) * mm4.z;
      const float p3 = exp2f(sacc[nj][3] * 0.18033688f) * mm4.w;
      den += (p0 + p1) + (p2 + p3);
      union { bf16 h[4]; uint2 u2; } pu;
      pu.h[0] = (bf16)p0; pu.h[1] = (bf16)p1; pu.h[2] = (bf16)p2; pu.h[3] = (bf16)p3;
      const int c4s = (nj*2 + (lq >> 1)) ^ (lc & 7);
      *(uint2*)(PsW + lc*128 + (c4s << 4) + ((lq & 1) << 3)) = pu.u2;
    }

    // O += P V  (pf: A-frag row q=lc, j-slice kk*32+lq*8, swizzle-consistent)
#pragma unroll
    for (int kk = 0; kk < 2; kk++) {
      bf16x8 pf = *(const bf16x8*)(PsW + lc*128 + ((((kk << 2) + lq) ^ (lc & 7)) << 4));
#pragma unroll
      for (int di = 0; di < 4; di++) {
        bf16x8 vf = *(const bf16x8*)&VTs[c][(di*16 + lc) * 64 + SWZ(lc, kk*4 + lq)*8];
        oacc[di] = __builtin_amdgcn_mfma_f32_16x16x32_bf16(pf, vf, oacc[di], 0, 0, 0);
      }
    }

    __builtin_amdgcn_s_barrier();           // all waves done with buf c
    if (t + 2 < JD/64) {
      stKV(c, t + 2);
      VMW(2);                               // tile t+1 landed; t+2 in flight
    } else if (t + 1 < JD/64) {
      VMW(0);                               // drain last prefetch
    }
    __builtin_amdgcn_s_barrier();
  }

  // denominator: lanes sharing lc hold partial sums for q=lc
  den += __shfl_xor(den, 16);
  den += __shfl_xor(den, 32);
  const float rden = 1.0f / den;

#pragma unroll
  for (int di = 0; di < 4; di++) {
    const int col = h*64 + di*16 + lc;
#pragma unroll
    for (int r = 0; r < 4; r++) {
      const float dr = __shfl(rden, lq*4 + r, 16);   // rden of q = lq*4+r
      const int i = qt*128 + w*16 + lq*4 + r;
      outp[(size_t)(b*MQ + i) * 1024 + col] = (bf16)(oacc[di][r] * dr);
    }
  }
}

// ---------------- launch -----------------------------------------------------
extern "C" void kernel_launch(void* const* d_in, const int* in_sizes, int n_in,
                              void* d_out, int out_size, void* d_ws, size_t ws_size,
                              hipStream_t stream)
{
  const float* x    = (const float*)d_in[0];
  const float* lat  = (const float*)d_in[1];
  const void*  mraw = d_in[2];
  const float* nm_g = (const float*)d_in[3];
  const float* nm_b = (const float*)d_in[4];
  const float* nl_g = (const float*)d_in[5];
  const float* nl_b = (const float*)d_in[6];
  const float* Wq   = (const float*)d_in[7];
  const float* Wkv  = (const float*)d_in[8];
  const float* Wo   = (const float*)d_in[9];
  float* out = (float*)d_out;

  char* p = (char*)d_ws;
  auto alloc = [&](size_t bytes) { char* r = p; p += (bytes + 255) & ~(size_t)255; return r; };

  bf16*  kv_in  = (bf16*)alloc((size_t)NB * JD * DIMV * 2);          // 71.3 MB
  bf16*  Krows  = (bf16*)alloc((size_t)NB * JD * 1024 * 2);          // 71.3 MB
  bf16*  VTbuf  = (bf16*)alloc((size_t)NB * HEADS * 64 * JD * 2);    // 71.3 MB
  bf16*  WqT    = (bf16*)alloc((size_t)1024 * 1024 * 2);
  bf16*  WkvT   = (bf16*)alloc((size_t)2048 * 1024 * 2);
  bf16*  WoT    = (bf16*)alloc((size_t)1024 * 1024 * 2);
  bf16*  ln_buf = (bf16*)alloc((size_t)NB * MQ * DIMV * 2);
  bf16*  Qrows  = (bf16*)alloc((size_t)NB * MQ * 1024 * 2);
  bf16*  attout = (bf16*)alloc((size_t)NB * MQ * DIMV * 2);
  float* mmulp  = (float*)alloc((size_t)NB * JD * 4);
  int*   flag   = (int*)alloc(256);
  (void)ws_size; (void)in_sizes; (void)n_in; (void)out_size;

  ln_kernel<<<NB * MX, 256, 0, stream>>>(x,   nm_g, nm_b, kv_in, nullptr, 0);
  ln_kernel<<<NB * MQ, 256, 0, stream>>>(lat, nl_g, nl_b, kv_in, ln_buf, 1);
  transpose_w<<<256, 256, 0, stream>>>(Wq,  WqT,  1024, 1024);
  transpose_w<<<512, 256, 0, stream>>>(Wkv, WkvT, 1024, 2048);
  transpose_w<<<256, 256, 0, stream>>>(Wo,  WoT,  1024, 1024);
  mask_detect<<<1, 256, 0, stream>>>((const unsigned char*)mraw, 32768, flag);
  mask_build<<<136, 256, 0, stream>>>(mraw, flag, mmulp);

  // kv = kv_in @ Wkv (K rows + V^T) AND q = ln @ Wq, all as 256^2 tiles:
  // 1088 KV tiles + 32 Q tiles = 1120 blocks (%8==0 for XCD swizzle).
  gemm256<<<1120, 512, 0, stream>>>(kv_in, WkvT, ln_buf, WqT, Krows, VTbuf, Qrows);
  attn_kernel<<<256, 512, 0, stream>>>(Qrows, Krows, VTbuf, mmulp, attout);
  // out = attout @ Wo -> f32 d_out
  gemm128<<<dim3(8, 16), 256, 0, stream>>>(attout, WoT, out, 1024);
}

// Round 6
// 522.811 us; speedup vs baseline: 1.0444x; 1.0033x over previous
//
#include <hip/hip_runtime.h>
#include <hip/hip_bf16.h>
#include <stdint.h>

// Problem constants
#define HEADS 16
#define DH    64
#define NB    8
#define MQ    256     // latents per batch
#define MX    4096    // media tokens per batch
#define JD    4352    // MX + MQ
#define DIMV  1024
#define GK    1024    // K dim of every GEMM in this problem (compile-time)

typedef __bf16 bf16;
typedef __bf16 bf16x8 __attribute__((ext_vector_type(8)));
typedef float  f32x4  __attribute__((ext_vector_type(4)));

// XOR swizzle of 16B chunks within a 64-col (8-chunk) LDS row: spreads the
// stride-128B row aliasing across all banks. Same formula on stage + read.
#define SWZ(r, c) (((c) ^ ((r) & 7)))

#define VMW(n) asm volatile("s_waitcnt vmcnt(" #n ")" ::: "memory")

__device__ __forceinline__ void gl_lds16(const void* g, void* l) {
  __builtin_amdgcn_global_load_lds((const __attribute__((address_space(1))) void*)g,
                                   (__attribute__((address_space(3))) void*)l, 16, 0, 0);
}

// ---------------- LayerNorm (f32 in, bf16 out) -------------------------------
__global__ __launch_bounds__(256) void ln_kernel(
    const float* __restrict__ X, const float* __restrict__ gw, const float* __restrict__ bw,
    bf16* __restrict__ out_kv, bf16* __restrict__ out_ln, int is_lat)
{
  const int row = blockIdx.x;
  const int tid = threadIdx.x;
  const float4 v = ((const float4*)(X + (size_t)row * DIMV))[tid];
  float s  = v.x + v.y + v.z + v.w;
  float s2 = v.x*v.x + v.y*v.y + v.z*v.z + v.w*v.w;
#pragma unroll
  for (int m = 1; m < 64; m <<= 1) { s += __shfl_xor(s, m); s2 += __shfl_xor(s2, m); }
  __shared__ float red[8];
  const int wid = tid >> 6;
  if ((tid & 63) == 0) { red[wid*2] = s; red[wid*2+1] = s2; }
  __syncthreads();
  s  = red[0] + red[2] + red[4] + red[6];
  s2 = red[1] + red[3] + red[5] + red[7];
  const float mu  = s * (1.0f / DIMV);
  const float var = s2 * (1.0f / DIMV) - mu * mu;
  const float rst = rsqrtf(var + 1e-5f);
  const float4 g4 = ((const float4*)gw)[tid];
  const float4 b4 = ((const float4*)bw)[tid];
  union { bf16 h[4]; short4 s4; } u;
  u.h[0] = (bf16)((v.x - mu) * rst * g4.x + b4.x);
  u.h[1] = (bf16)((v.y - mu) * rst * g4.y + b4.y);
  u.h[2] = (bf16)((v.z - mu) * rst * g4.z + b4.z);
  u.h[3] = (bf16)((v.w - mu) * rst * g4.w + b4.w);
  size_t kvrow;
  if (is_lat) { int b = row >> 8;  int i = row & 255;  kvrow = (size_t)b * JD + MX + i; }
  else        { int b = row >> 12; int j = row & 4095; kvrow = (size_t)b * JD + j; }
  *(short4*)(out_kv + kvrow * DIMV + tid * 4) = u.s4;
  if (is_lat) *(short4*)(out_ln + (size_t)row * DIMV + tid * 4) = u.s4;
}

// ---------------- Weight transpose + f32->bf16: in[R][C] -> out[C][R] --------
__global__ __launch_bounds__(256) void transpose_w(
    const float* __restrict__ in, bf16* __restrict__ out, int R, int C)
{
  __shared__ float t[64][65];
  const int tilesC = C >> 6;
  const int tc = blockIdx.x % tilesC, tr = blockIdx.x / tilesC;
  const int r0 = tr << 6, c0 = tc << 6;
  const int lr = threadIdx.x >> 4;
  const int lc = (threadIdx.x & 15) << 2;
#pragma unroll
  for (int p = 0; p < 4; p++) {
    float4 v = *(const float4*)&in[(size_t)(r0 + lr + p*16) * C + c0 + lc];
    t[lr + p*16][lc    ] = v.x; t[lr + p*16][lc + 1] = v.y;
    t[lr + p*16][lc + 2] = v.z; t[lr + p*16][lc + 3] = v.w;
  }
  __syncthreads();
#pragma unroll
  for (int p = 0; p < 4; p++) {
    const int oc = lr + p*16;
    union { bf16 h[4]; short4 s4; } u;
    u.h[0] = (bf16)t[lc    ][oc]; u.h[1] = (bf16)t[lc + 1][oc];
    u.h[2] = (bf16)t[lc + 2][oc]; u.h[3] = (bf16)t[lc + 3][oc];
    *(short4*)&out[(size_t)(c0 + oc) * R + r0 + lc] = u.s4;
  }
}

// ---------------- mask dtype detect + build ---------------------------------
__global__ __launch_bounds__(256) void mask_detect(
    const unsigned char* __restrict__ m, int n, int* __restrict__ flag)
{
  const int tid = threadIdx.x;
  int cnt = 0;
  for (int i = tid; i < n; i += 256) cnt += (m[i] != 0) ? 1 : 0;
#pragma unroll
  for (int mm = 1; mm < 64; mm <<= 1) cnt += __shfl_xor(cnt, mm);
  __shared__ int r4[4];
  if ((tid & 63) == 0) r4[tid >> 6] = cnt;
  __syncthreads();
  if (tid == 0) {
    int t = r4[0] + r4[1] + r4[2] + r4[3];
    flag[0] = (t * 16 > n * 5) ? 1 : 0;   // frac > 0.3125 -> byte mode
  }
}

// madd[b][j] = masked ? -20000 : 0  (additive log-domain mask; exp2 flushes
// exactly to 0.0f at -20000, so arithmetic is identical to the 0/1 multiplier)
__global__ __launch_bounds__(256) void mask_build(
    const void* __restrict__ mraw, const int* __restrict__ flag, float* __restrict__ madd)
{
  const int idx = blockIdx.x * 256 + threadIdx.x;   // < 34816
  const int b = idx / JD, j = idx - b * JD;
  float v = 0.0f;
  if (j < MX) {
    bool masked = (*flag) ? (((const unsigned char*)mraw)[b * MX + j] != 0)
                          : (((const int*)mraw)[b * MX + j] != 0);
    v = masked ? -20000.0f : 0.0f;
  }
  madd[idx] = v;
}

// ---------------- GEMM: 256x256 tile, BK=64, m201-faithful 8-phase pipeline --
// (round-2 schedule, best measured: 175 us, VGPR 116 — read-ahead reverted)
__global__ __launch_bounds__(512, 2) void gemm256(
    const bf16* __restrict__ A, const bf16* __restrict__ Bt,
    const bf16* __restrict__ Aq, const bf16* __restrict__ Bq,
    bf16* __restrict__ outR, bf16* __restrict__ outVT, bf16* __restrict__ outQ)
{
  __shared__ bf16 sm[65536];                 // 128 KiB: [d][A 16384 | B 16384]

  const int tid = threadIdx.x;
  const int lane = tid & 63, wid = tid >> 6;
  const int wr = wid >> 2, wc = wid & 3;     // 2 x 4 wave grid
  const int lc = lane & 15, lq = lane >> 4;
  const int srow = tid >> 3, sc = tid & 7;
  const int ssw = SWZ(srow, sc) * 8;

  // XCD-bijective swizzle (1120 % 8 == 0): contiguous tile chunk per XCD.
  int bid = blockIdx.x;
  bid = (bid & 7) * 140 + (bid >> 3);

  const bf16 *Arow, *Brow;
  int m0, n0, omode;
  if (bid < 1088) {
    const int by = bid >> 3, bx = bid & 7;
    m0 = by * 256;
    if (bx < 4) { n0 = bx * 256;
      Arow = A  + (size_t)m0 * GK; Brow = Bt + (size_t)n0 * GK; omode = 0; }
    else        { n0 = 1024 + (bx - 4) * 256;
      Arow = Bt + (size_t)n0 * GK; Brow = A  + (size_t)m0 * GK; omode = 1; }
  } else {
    const int ix = bid - 1088;
    m0 = (ix >> 2) * 256; n0 = (ix & 3) * 256;
    Arow = Aq + (size_t)m0 * GK; Brow = Bq + (size_t)n0 * GK; omode = 2;
  }

  const bf16* Abase = Arow + (size_t)srow * GK + ssw;
  const bf16* Bbase = Brow + (size_t)srow * GK + ssw;

  // stage one 128-row half-tile (2 x global_load_lds per thread)
  auto stA = [&](int d, int h, int kt) {
#pragma unroll
    for (int l = 0; l < 2; ++l)
      gl_lds16(Abase + (size_t)(h*128 + l*64) * GK + kt * 64,
               &sm[d*32768 + (h*128 + l*64)*64 + tid*8]);
  };
  auto stB = [&](int d, int h, int kt) {
#pragma unroll
    for (int l = 0; l < 2; ++l)
      gl_lds16(Bbase + (size_t)(h*128 + l*64) * GK + kt * 64,
               &sm[d*32768 + 16384 + (h*128 + l*64)*64 + tid*8]);
  };

  f32x4 acc[8][4];
#pragma unroll
  for (int i = 0; i < 8; i++)
#pragma unroll
    for (int j = 0; j < 4; j++)
#pragma unroll
      for (int r = 0; r < 4; r++) acc[i][j][r] = 0.f;

#define DS_PHASE(d, q, STAGE_STMT, WAIT_STMT)                                  \
  {                                                                            \
    const bf16* As_ = sm + (d)*32768;                                          \
    const bf16* Bs_ = sm + (d)*32768 + 16384;                                  \
    bf16x8 af[2][2];                                                           \
    _Pragma("unroll") for (int mi = 0; mi < 2; ++mi)                           \
      _Pragma("unroll") for (int kk = 0; kk < 2; ++kk)                         \
        af[mi][kk] = *(const bf16x8*)&As_[(wr*128 + ((q)*2+mi)*16 + lc)*64 +   \
                                          SWZ(lc, kk*4 + lq)*8];               \
    if ((q) == 0) {                                                            \
      _Pragma("unroll") for (int n = 0; n < 4; ++n)                            \
        _Pragma("unroll") for (int kk = 0; kk < 2; ++kk)                       \
          bfrag[n][kk] = *(const bf16x8*)&Bs_[(wc*64 + n*16 + lc)*64 +         \
                                              SWZ(lc, kk*4 + lq)*8];           \
    }                                                                          \
    STAGE_STMT;                                                                \
    WAIT_STMT;                                                                 \
    __builtin_amdgcn_s_barrier();                                              \
    __builtin_amdgcn_s_setprio(1);                                             \
    _Pragma("unroll") for (int kk = 0; kk < 2; ++kk)                           \
      _Pragma("unroll") for (int mi = 0; mi < 2; ++mi)                         \
        _Pragma("unroll") for (int n = 0; n < 4; ++n)                          \
          acc[(q)*2+mi][n] = __builtin_amdgcn_mfma_f32_16x16x32_bf16(          \
              af[mi][kk], bfrag[n][kk], acc[(q)*2+mi][n], 0, 0, 0);            \
    __builtin_amdgcn_s_setprio(0);                                             \
    __builtin_amdgcn_s_barrier();                                              \
  }

  // Prologue: tile0 B+A, tile1 B; wait leaves tile1's B (4 loads) in flight.
  stB(0, 0, 0); stB(0, 1, 0);
  stA(0, 0, 0); stA(0, 1, 0);
  stB(1, 0, 1); stB(1, 1, 1);
  VMW(4);
  __builtin_amdgcn_s_barrier();

  bf16x8 bfrag[4][2];
#pragma unroll 1
  for (int it = 0; it < 8; ++it) {
    const int tb = 2*it + 1, ta2 = 2*it + 2, tb2 = 2*it + 3;
    const bool s2 = (ta2 < 16), s3 = (tb2 < 16);
    DS_PHASE(0, 0, { stA(1, 0, tb); stA(1, 1, tb); }, {});
    DS_PHASE(0, 1, { if (s2) stB(0, 0, ta2); }, {});
    DS_PHASE(0, 2, { if (s2) stB(0, 1, ta2); }, {});
    DS_PHASE(0, 3, {}, { if (s2) { VMW(4); } else { VMW(0); } });
    DS_PHASE(1, 0, { if (s2) stA(0, 0, ta2); }, {});
    DS_PHASE(1, 1, { if (s2) stA(0, 1, ta2); }, {});
    DS_PHASE(1, 2, { if (s3) stB(1, 0, tb2); }, {});
    DS_PHASE(1, 3, { if (s3) stB(1, 1, tb2); }, { if (s3) { VMW(4); } });
  }
#undef DS_PHASE

  // ---- Epilogue: acc -> bf16 Ct[256][256] in LDS (32-chunk swizzle), then
  //      coalesced 16B row-major stores.
  __syncthreads();
  bf16* Ct = sm;
#pragma unroll
  for (int m = 0; m < 8; ++m)
#pragma unroll
    for (int n = 0; n < 4; ++n) {
      const int col = wc*64 + n*16 + lc;
      const int cch = col >> 3, cw = col & 7;
#pragma unroll
      for (int r = 0; r < 4; ++r) {
        const int row = wr*128 + m*16 + lq*4 + r;
        Ct[row*256 + (((cch ^ (row & 31)) << 3) + cw)] = (bf16)acc[m][n][r];
      }
    }
  __syncthreads();

  const int cch = tid & 31, r0 = tid >> 5;
  if (omode != 1) {
    bf16* dst0 = (omode == 0 ? outR : outQ);
#pragma unroll
    for (int i = 0; i < 16; ++i) {
      const int row = r0 + i*16;
      bf16x8 v = *(const bf16x8*)&Ct[row*256 + ((cch ^ (row & 31)) << 3)];
      *(bf16x8*)(dst0 + (size_t)(m0 + row) * 1024 + n0 + cch*8) = v;
    }
  } else {
    const int bb = m0 / JD;                // 256-row m-tiles never cross batches (JD = 17*256)
    const int jbase = m0 - bb * JD;
#pragma unroll
    for (int i = 0; i < 16; ++i) {
      const int row = r0 + i*16;
      const int cc = n0 + row - 1024;      // weight col in V half
      bf16x8 v = *(const bf16x8*)&Ct[row*256 + ((cch ^ (row & 31)) << 3)];
      bf16* dst = outVT + (((size_t)(bb*HEADS + (cc >> 6)))*64 + (cc & 63)) * JD
                        + jbase + cch*8;
      *(bf16x8*)dst = v;
    }
  }
}

// ---------------- GEMM: 128x128 tile, BK=64 (final projection, f32 out) -----
__global__ __launch_bounds__(256) void gemm128(
    const bf16* __restrict__ A, const bf16* __restrict__ Bt,
    float* __restrict__ Cf, int N)
{
  __shared__ bf16 smem[2 * 128 * 64];
  bf16* As = smem;
  bf16* Bs = smem + 128 * 64;

  const int tid = threadIdx.x;
  const int lane = tid & 63, wid = tid >> 6;
  const int wr = wid >> 1, wc = wid & 1;
  const int m0 = blockIdx.y * 128;
  const int n0 = blockIdx.x * 128;
  const int srow = tid >> 3, sc = tid & 7;
  const int ssw = SWZ(srow, sc) * 8;     // swizzled source chunk (elements)
  const int lc = lane & 15, lq = lane >> 4;

  f32x4 acc[4][4];
#pragma unroll
  for (int i = 0; i < 4; i++)
#pragma unroll
    for (int j = 0; j < 4; j++)
#pragma unroll
      for (int r = 0; r < 4; r++) acc[i][j][r] = 0.f;

  const bf16* Abase = A + (size_t)m0 * GK + (size_t)srow * GK + ssw;
  const bf16* Bbase = Bt + (size_t)n0 * GK + (size_t)srow * GK + ssw;

  for (int k0 = 0; k0 < GK; k0 += 64) {
    __syncthreads();
#pragma unroll
    for (int q = 0; q < 4; q++) {
      gl_lds16(Abase + (size_t)q * 32 * GK + k0, &As[(srow + q*32) * 64 + sc*8]);
      gl_lds16(Bbase + (size_t)q * 32 * GK + k0, &Bs[(srow + q*32) * 64 + sc*8]);
    }
    VMW(0);
    __syncthreads();
#pragma unroll
    for (int kk = 0; kk < 2; kk++) {
      bf16x8 af[4], bfr[4];
#pragma unroll
      for (int mi = 0; mi < 4; mi++)
        af[mi] = *(const bf16x8*)&As[(wr*64 + mi*16 + lc) * 64 + SWZ(lc, kk*4 + lq)*8];
#pragma unroll
      for (int ni = 0; ni < 4; ni++)
        bfr[ni] = *(const bf16x8*)&Bs[(wc*64 + ni*16 + lc) * 64 + SWZ(lc, kk*4 + lq)*8];
#pragma unroll
      for (int mi = 0; mi < 4; mi++)
#pragma unroll
        for (int ni = 0; ni < 4; ni++)
          acc[mi][ni] = __builtin_amdgcn_mfma_f32_16x16x32_bf16(af[mi], bfr[ni], acc[mi][ni], 0, 0, 0);
    }
  }

#pragma unroll
  for (int mi = 0; mi < 4; mi++)
#pragma unroll
    for (int ni = 0; ni < 4; ni++) {
      const int r = m0 + wr*64 + mi*16 + lq*4;
      const int c = n0 + wc*64 + ni*16 + lc;
#pragma unroll
      for (int reg = 0; reg < 4; reg++)
        Cf[(size_t)(r + reg) * N + c] = acc[mi][ni][reg];
    }
}

// ---------------- Attention --------------------------------------------------
// 256 blocks = (b,h) x 2 q-tiles of 128; 512 threads (8 waves, 16 q-rows each).
// Swapped QK^T (S^T layout): lane holds 4 consecutive j for fixed q=lane&15.
// K/V 4-deep LDS pipeline, counted vmcnt(6) (3 tiles in flight). The additive
// mask row is staged to LDS ONCE in the prologue -> per-tile mask access is
// ds_read (lgkmcnt), so NO global load ever pollutes the vmcnt ledger.
__global__ __launch_bounds__(512) void attn_kernel(
    const bf16* __restrict__ Qrows,  // [2048][1024]
    const bf16* __restrict__ Krows,  // [B*JD][1024]
    const bf16* __restrict__ VT,     // [B][H][64][JD]
    const float* __restrict__ madd,  // [B][JD] additive mask (0 / -20000)
    bf16* __restrict__ outp)         // [2048][1024]
{
  const int bh = blockIdx.x >> 1, qt = blockIdx.x & 1;
  const int b = bh >> 4, h = bh & 15;
  __shared__ bf16 Qs[128 * 64];
  __shared__ bf16 Ks[4][64 * 64];
  __shared__ bf16 VTs[4][64 * 64];
  __shared__ bf16 Ps[8][16 * 64];
  __shared__ float Madd[JD];               // 17408 B
  const int tid = threadIdx.x, lane = tid & 63, w = tid >> 6;
  const int lc = lane & 15, lq = lane >> 4;
  const int srow = tid >> 3, sc = tid & 7;
  const int ssw = SWZ(srow, sc) * 8;

  const bf16* Qg = Qrows + ((size_t)(b*MQ + qt*128)) * 1024 + h*64;
  const bf16* Kg = Krows + ((size_t)b * JD) * 1024 + h*64;
  const bf16* Vg = VT + ((size_t)bh * 64) * JD;
  const float* mp = madd + (size_t)b * JD;

  auto stKV = [&](int c, int t) {
    gl_lds16(Kg + (size_t)(t*64 + srow) * 1024 + ssw, &Ks[c][tid*8]);
    gl_lds16(Vg + (size_t)srow * JD + t*64 + ssw, &VTs[c][tid*8]);
  };

  // Prologue: Q + mask row (drain once), then 4 KV tiles with counted wait.
  gl_lds16(Qg + (size_t)srow * 1024 + ssw, &Qs[tid*8]);
  gl_lds16(Qg + (size_t)(srow + 64) * 1024 + ssw, &Qs[(tid + 512)*8]);
  gl_lds16(mp + tid*4,        &Madd[tid*4]);
  gl_lds16(mp + 2048 + tid*4, &Madd[2048 + tid*4]);
  if (tid < 64) gl_lds16(mp + 4096 + tid*4, &Madd[4096 + tid*4]);
  VMW(0);
  stKV(0, 0); stKV(1, 1); stKV(2, 2); stKV(3, 3);
  VMW(6);                                   // tile0 landed; tiles 1-3 in flight
  __syncthreads();

  bf16x8 qf[2];
#pragma unroll
  for (int kk = 0; kk < 2; kk++)
    qf[kk] = *(const bf16x8*)&Qs[(w*16 + lc) * 64 + SWZ(lc, kk*4 + lq)*8];

  char* PsW = (char*)&Ps[w][0];
  f32x4 oacc[4];
  float den = 0.f;
#pragma unroll
  for (int di = 0; di < 4; di++)
#pragma unroll
    for (int r = 0; r < 4; r++) oacc[di][r] = 0.f;

#pragma unroll 1
  for (int t = 0; t < JD/64; ++t) {
    const int c = t & 3;
    const int j0 = t * 64;

    // S^T = K Q^T (swapped operands): sacc[nj][r] = S[q=lc][j0 + nj*16 + lq*4 + r]
    f32x4 sacc[4];
#pragma unroll
    for (int nj = 0; nj < 4; nj++)
#pragma unroll
      for (int r = 0; r < 4; r++) sacc[nj][r] = 0.f;
#pragma unroll
    for (int kk = 0; kk < 2; kk++) {
      bf16x8 kf[4];
#pragma unroll
      for (int nj = 0; nj < 4; nj++)
        kf[nj] = *(const bf16x8*)&Ks[c][(nj*16 + lc) * 64 + SWZ(lc, kk*4 + lq)*8];
#pragma unroll
      for (int nj = 0; nj < 4; nj++)
        sacc[nj] = __builtin_amdgcn_mfma_f32_16x16x32_bf16(kf[nj], qf[kk], sacc[nj], 0, 0, 0);
    }

    // P = exp2(S*c + madd) ; lane-local denominator ; packed b64 P-stage
#pragma unroll
    for (int nj = 0; nj < 4; nj++) {
      const float4 ma4 = *(const float4*)&Madd[j0 + nj*16 + lq*4];
      // scale * log2(e) = 0.125 * 1.4426950 = 0.18033688
      const float p0 = exp2f(fmaf(sacc[nj][0], 0.18033688f, ma4.x));
      const float p1 = exp2f(fmaf(sacc[nj][1], 0.18033688f, ma4.y));
      const float p2 = exp2f(fmaf(sacc[nj][2], 0.18033688f, ma4.z));
      const float p3 = exp2f(fmaf(sacc[nj][3], 0.18033688f, ma4.w));
      den += (p0 + p1) + (p2 + p3);
      union { bf16 h[4]; uint2 u2; } pu;
      pu.h[0] = (bf16)p0; pu.h[1] = (bf16)p1; pu.h[2] = (bf16)p2; pu.h[3] = (bf16)p3;
      const int c4s = (nj*2 + (lq >> 1)) ^ (lc & 7);
      *(uint2*)(PsW + lc*128 + (c4s << 4) + ((lq & 1) << 3)) = pu.u2;
    }

    // O += P V  (pf: A-frag row q=lc, j-slice kk*32+lq*8, swizzle-consistent)
#pragma unroll
    for (int kk = 0; kk < 2; kk++) {
      bf16x8 pf = *(const bf16x8*)(PsW + lc*128 + ((((kk << 2) + lq) ^ (lc & 7)) << 4));
#pragma unroll
      for (int di = 0; di < 4; di++) {
        bf16x8 vf = *(const bf16x8*)&VTs[c][(di*16 + lc) * 64 + SWZ(lc, kk*4 + lq)*8];
        oacc[di] = __builtin_amdgcn_mfma_f32_16x16x32_bf16(pf, vf, oacc[di], 0, 0, 0);
      }
    }

    __builtin_amdgcn_s_barrier();           // all waves done with buf c
    if (t + 4 < JD/64) {
      stKV(c, t + 4);
      VMW(6);                               // t+1 landed; t+2..t+4 in flight
    } else if (t == JD/64 - 4) { VMW(4);    // t+1 landed; t+2,t+3 in flight
    } else if (t == JD/64 - 3) { VMW(2);
    } else if (t == JD/64 - 2) { VMW(0);
    }
    __builtin_amdgcn_s_barrier();
  }

  // denominator: lanes sharing lc hold partial sums for q=lc
  den += __shfl_xor(den, 16);
  den += __shfl_xor(den, 32);
  const float rden = 1.0f / den;

#pragma unroll
  for (int di = 0; di < 4; di++) {
    const int col = h*64 + di*16 + lc;
#pragma unroll
    for (int r = 0; r < 4; r++) {
      const float dr = __shfl(rden, lq*4 + r, 16);   // rden of q = lq*4+r
      const int i = qt*128 + w*16 + lq*4 + r;
      outp[(size_t)(b*MQ + i) * 1024 + col] = (bf16)(oacc[di][r] * dr);
    }
  }
}

// ---------------- launch -----------------------------------------------------
extern "C" void kernel_launch(void* const* d_in, const int* in_sizes, int n_in,
                              void* d_out, int out_size, void* d_ws, size_t ws_size,
                              hipStream_t stream)
{
  const float* x    = (const float*)d_in[0];
  const float* lat  = (const float*)d_in[1];
  const void*  mraw = d_in[2];
  const float* nm_g = (const float*)d_in[3];
  const float* nm_b = (const float*)d_in[4];
  const float* nl_g = (const float*)d_in[5];
  const float* nl_b = (const float*)d_in[6];
  const float* Wq   = (const float*)d_in[7];
  const float* Wkv  = (const float*)d_in[8];
  const float* Wo   = (const float*)d_in[9];
  float* out = (float*)d_out;

  char* p = (char*)d_ws;
  auto alloc = [&](size_t bytes) { char* r = p; p += (bytes + 255) & ~(size_t)255; return r; };

  bf16*  kv_in  = (bf16*)alloc((size_t)NB * JD * DIMV * 2);          // 71.3 MB
  bf16*  Krows  = (bf16*)alloc((size_t)NB * JD * 1024 * 2);          // 71.3 MB
  bf16*  VTbuf  = (bf16*)alloc((size_t)NB * HEADS * 64 * JD * 2);    // 71.3 MB
  bf16*  WqT    = (bf16*)alloc((size_t)1024 * 1024 * 2);
  bf16*  WkvT   = (bf16*)alloc((size_t)2048 * 1024 * 2);
  bf16*  WoT    = (bf16*)alloc((size_t)1024 * 1024 * 2);
  bf16*  ln_buf = (bf16*)alloc((size_t)NB * MQ * DIMV * 2);
  bf16*  Qrows  = (bf16*)alloc((size_t)NB * MQ * 1024 * 2);
  bf16*  attout = (bf16*)alloc((size_t)NB * MQ * DIMV * 2);
  float* maddp  = (float*)alloc((size_t)NB * JD * 4);
  int*   flag   = (int*)alloc(256);
  (void)ws_size; (void)in_sizes; (void)n_in; (void)out_size;

  ln_kernel<<<NB * MX, 256, 0, stream>>>(x,   nm_g, nm_b, kv_in, nullptr, 0);
  ln_kernel<<<NB * MQ, 256, 0, stream>>>(lat, nl_g, nl_b, kv_in, ln_buf, 1);
  transpose_w<<<256, 256, 0, stream>>>(Wq,  WqT,  1024, 1024);
  transpose_w<<<512, 256, 0, stream>>>(Wkv, WkvT, 1024, 2048);
  transpose_w<<<256, 256, 0, stream>>>(Wo,  WoT,  1024, 1024);
  mask_detect<<<1, 256, 0, stream>>>((const unsigned char*)mraw, 32768, flag);
  mask_build<<<136, 256, 0, stream>>>(mraw, flag, maddp);

  // kv = kv_in @ Wkv (K rows + V^T) AND q = ln @ Wq, all as 256^2 tiles:
  // 1088 KV tiles + 32 Q tiles = 1120 blocks (%8==0 for XCD swizzle).
  gemm256<<<1120, 512, 0, stream>>>(kv_in, WkvT, ln_buf, WqT, Krows, VTbuf, Qrows);
  attn_kernel<<<256, 512, 0, stream>>>(Qrows, Krows, VTbuf, maddp, attout);
  // out = attout @ Wo -> f32 d_out
  gemm128<<<dim3(8, 16), 256, 0, stream>>>(attout, WoT, out, 1024);
}